// Round 6
// baseline (619.118 us; speedup 1.0000x reference)
//
#include <hip/hip_runtime.h>
#include <hip/hip_bf16.h>

// Dims: B=64, T=512, V=512, H=256, O=512. M1 = B*T = 32768.
// d_in: sentence, prev_state, W_ih, b_ih, W_hh, b_hh, W_out, b_out
// d_out: tags [B,T,O] fp32 (16777216) then h_n [1,B,H] fp32 (16384)
//
// Round 6:
//  - RNN: 4 waves x 4 n-tiles (was 8 waves x 2). The h-fragments read from
//    LDS are IDENTICAL across waves (only the in-register W n-slice differs),
//    so 8 waves redundantly read the same tile 8x: 64 ds_read_b128/block-step
//    ~ 770 cyc of the ~1700-cyc step. 4 waves halve that. W frags = 128
//    VGPR/wave -> launch_bounds(256,1). Barrier syncs 4 waves, not 8.
//  - GEMMs: revert to round-3 shape (512 thr, 128 KB stage; round-5's
//    2-blocks/CU variant was neutral/worse). Keep cap-in-gemm3.

typedef __attribute__((ext_vector_type(8))) _Float16 half8;
typedef __attribute__((ext_vector_type(4))) _Float16 half4;
typedef __attribute__((ext_vector_type(4))) float   floatx4;

// LDS-only barrier: waits LDS ops, does NOT drain vmcnt — global loads/stores
// stay in flight across it.
__device__ __forceinline__ void lds_barrier() {
    asm volatile("s_waitcnt lgkmcnt(0)\n\ts_barrier" ::: "memory");
}

// ---------------- fp32 -> fp16 convert: W_ih and W_out in one launch ----------------
__global__ void conv_weights(const float* __restrict__ wih, const float* __restrict__ wout,
                             _Float16* __restrict__ out) {
    int idx = blockIdx.x * blockDim.x + threadIdx.x;   // 0..65535 quads
    const float* src = (idx < 32768) ? wih : wout;
    int j = idx & 32767;
    float4 v = ((const float4*)src)[j];
    half4 h = { (_Float16)v.x, (_Float16)v.y, (_Float16)v.z, (_Float16)v.w };
    ((half4*)out)[idx] = h;
}

// Stage 256 LDS rows x 512 B from f16 weights, XOR-swizzled within each row.
// LDS dest linear (global_load_lds requirement, m104); swizzle applied to the
// per-lane GLOBAL source address (m173). 512 threads.
__device__ __forceinline__ void stage_weights_swz(const _Float16* __restrict__ src,
                                                  int rowStrideHalves,
                                                  _Float16* lds) {
    int wave = threadIdx.x >> 6;
    int lane = threadIdx.x & 63;
#pragma unroll
    for (int j = 0; j < 16; j++) {
        int Lb = j * 8192 + wave * 1024 + lane * 16;   // this lane's LDS byte
        int n  = Lb >> 9;
        int c  = Lb & 511;
        int cs = c ^ ((n & 7) << 4);
        const _Float16* g = src + (size_t)n * rowStrideHalves + (cs >> 1);
        _Float16* l = lds + (j * 8192 + wave * 1024) / 2;   // wave-uniform base
        __builtin_amdgcn_global_load_lds((const __attribute__((address_space(1))) void*)g,
                                         (__attribute__((address_space(3))) void*)l,
                                         16, 0, 0);
    }
    asm volatile("s_waitcnt vmcnt(0)" ::: "memory");
    __syncthreads();
}

// ---------------- GEMM1: xproj = sentence [32768,512] @ W_ih^T + (b_ih+b_hh) ----------------
// 512 thr (8 waves), M-tile 128, K split in two 128-KB LDS stages. (round-3 form)
__global__ __launch_bounds__(512, 2) void gemm1_xproj(const float* __restrict__ A,
                                                      const _Float16* __restrict__ Bw,  // W_ih f16 [256,512]
                                                      const float* __restrict__ b_ih,
                                                      const float* __restrict__ b_hh,
                                                      float* __restrict__ C) {          // [32768,256]
    const int K = 512, N = 256;
    __shared__ _Float16 ldsB[65536];     // 256 rows x 256 halves (one K-half), 128 KB
    int wave = threadIdx.x >> 6;
    int lane = threadIdx.x & 63;
    int row  = lane & 15;
    int quad = lane >> 4;
    int m0 = blockIdx.x * 128 + wave * 16;

    floatx4 acc[16];
#pragma unroll
    for (int i = 0; i < 16; i++) acc[i] = (floatx4){0.f, 0.f, 0.f, 0.f};

    const float* pa = A + (size_t)(m0 + row) * K + quad * 8;
    const char* lb = (const char*)ldsB;

    for (int h = 0; h < 2; h++) {
        if (h) __syncthreads();                       // all waves done reading half 0
        stage_weights_swz(Bw + h * 256, 512, ldsB);   // wih[:, h*256 : h*256+256]

        for (int kk = 0; kk < 256; kk += 32) {
            float4 a0 = *(const float4*)(pa + h * 256 + kk);
            float4 a1 = *(const float4*)(pa + h * 256 + kk + 4);
            half8 a = { (_Float16)a0.x, (_Float16)a0.y, (_Float16)a0.z, (_Float16)a0.w,
                        (_Float16)a1.x, (_Float16)a1.y, (_Float16)a1.z, (_Float16)a1.w };
#pragma unroll
            for (int nt = 0; nt < 16; nt++) {
                int n = nt * 16 + row;
                int byte = n * 512 + ((quad * 16 + kk * 2) ^ ((n & 7) << 4));
                half8 b = *(const half8*)(lb + byte);
                acc[nt] = __builtin_amdgcn_mfma_f32_16x16x32_f16(a, b, acc[nt], 0, 0, 0);
            }
        }
    }
#pragma unroll
    for (int nt = 0; nt < 16; nt++) {
        int n = nt * 16 + row;
        float bn = b_ih[n] + b_hh[n];
#pragma unroll
        for (int r = 0; r < 4; r++) {
            int m = m0 + quad * 4 + r;
            C[(size_t)m * N + n] = acc[nt][r] + bn;
        }
    }
}

// ---------------- Recurrence: 4 blocks x 16 batch rows, 256 threads (4 waves x 4 n-tiles) ----------------
__global__ __launch_bounds__(256, 1) void rnn_recur(const float* __restrict__ xp,    // [B,T,H] fp32 (bias incl.)
                                                    const float* __restrict__ h0,    // [1,B,H] fp32
                                                    const float* __restrict__ W_hh,  // [H,H] fp32
                                                    _Float16* __restrict__ hid,      // f16 [B,T,H] UNCAPPED
                                                    float* __restrict__ h_n) {       // [B,H] fp32
    const int Hh = 256, T = 512, LD = 264;   // LDS row stride in halves
    int b0   = blockIdx.x * 16;
    int wave = threadIdx.x >> 6;   // 0..3
    int lane = threadIdx.x & 63;
    int c    = lane & 15;          // batch col within tile
    int q    = lane >> 4;

    // W_hh fragments: wf[nt][kt], n = wave*64 + nt*16 + c, k = kt*32 + q*8
    // 128 VGPRs — the whole point: W stays in regs so h-frag LDS reads are
    // the only per-step LDS traffic, now 4x instead of 8x redundant.
    half8 wf[4][8];
#pragma unroll
    for (int nt = 0; nt < 4; nt++) {
        int n = wave * 64 + nt * 16 + c;
        const float* wr = W_hh + (size_t)n * Hh + q * 8;
#pragma unroll
        for (int kt = 0; kt < 8; kt++) {
            float4 x0 = *(const float4*)(wr + kt * 32);
            float4 x1 = *(const float4*)(wr + kt * 32 + 4);
            wf[nt][kt] = (half8){ (_Float16)x0.x, (_Float16)x0.y, (_Float16)x0.z, (_Float16)x0.w,
                                  (_Float16)x1.x, (_Float16)x1.y, (_Float16)x1.z, (_Float16)x1.w };
        }
    }

    __shared__ _Float16 hb[2][16][264];
    for (int idx = threadIdx.x; idx < 16 * 256; idx += 256) {
        int m = idx >> 8, k = idx & 255;
        hb[0][m][k] = (_Float16)h0[(size_t)(b0 + m) * Hh + k];
    }
    __syncthreads();   // once, before the loop

    const float* xpb = xp + (size_t)(b0 + c) * T * Hh;
    _Float16* hidb = hid + (size_t)(b0 + c) * T * Hh;

    int noff[4];
#pragma unroll
    for (int nt = 0; nt < 4; nt++) noff[nt] = wave * 64 + nt * 16 + q * 4;

    // two prefetch slots: slot0 = even steps, slot1 = odd steps
    float4 xq0[4], xq1[4];
#pragma unroll
    for (int nt = 0; nt < 4; nt++) {
        xq0[nt] = *(const float4*)(xpb + (size_t)0 * Hh + noff[nt]);
        xq1[nt] = *(const float4*)(xpb + (size_t)1 * Hh + noff[nt]);
    }
    const float* pf0 = xpb + 2 * Hh;   // slot0's next load: x[t+2]
    const float* pf1 = xpb + 3 * Hh;   // slot1's next load: x[t+3]
    _Float16* hp = hidb;               // hid row for current t, advanced per step

    auto do_step = [&](int parity, float4 (&xq)[4], const float*& pf,
                       bool prefetch, bool last) {
        const _Float16* hr = &hb[parity][0][0];
        // 8 independent zero-init chains (4 nt x {k-low, k-high}), depth 4.
        // xq added AFTER the chains (round-4 lesson: xq at chain head forces
        // a vmcnt drain right after the barrier).
        floatx4 aA[4], aB[4];
#pragma unroll
        for (int nt = 0; nt < 4; nt++) {
            aA[nt] = (floatx4){0.f,0.f,0.f,0.f};
            aB[nt] = (floatx4){0.f,0.f,0.f,0.f};
        }
#pragma unroll
        for (int kt = 0; kt < 4; kt++) {
            half8 hfA = *(const half8*)(hr + c * LD + kt * 32 + q * 8);
            half8 hfB = *(const half8*)(hr + c * LD + (kt + 4) * 32 + q * 8);
#pragma unroll
            for (int nt = 0; nt < 4; nt++) {
                aA[nt] = __builtin_amdgcn_mfma_f32_16x16x32_f16(wf[nt][kt],     hfA, aA[nt], 0, 0, 0);
                aB[nt] = __builtin_amdgcn_mfma_f32_16x16x32_f16(wf[nt][kt + 4], hfB, aB[nt], 0, 0, 0);
            }
        }

        _Float16* hw = &hb[parity ^ 1][0][0];
#pragma unroll
        for (int nt = 0; nt < 4; nt++) {
            floatx4 acc = aA[nt] + aB[nt];
            float v0 = fmaxf(acc[0] + xq[nt].x, 0.f);
            float v1 = fmaxf(acc[1] + xq[nt].y, 0.f);
            float v2 = fmaxf(acc[2] + xq[nt].z, 0.f);
            float v3 = fmaxf(acc[3] + xq[nt].w, 0.f);
            half4 hv = { (_Float16)v0, (_Float16)v1, (_Float16)v2, (_Float16)v3 };
            *(half4*)(hw + c * LD + noff[nt]) = hv;   // next step's B source
            *(half4*)(hp + noff[nt]) = hv;            // UNCAPPED hidden; gemm3 caps
            if (last) {
                float4 hn = { v0, v1, v2, v3 };
                *(float4*)(h_n + (size_t)(b0 + c) * Hh + noff[nt]) = hn;
            }
        }
        hp += Hh;
        if (prefetch) {
#pragma unroll
            for (int nt = 0; nt < 4; nt++)
                xq[nt] = *(const float4*)(pf + noff[nt]);
            pf += 2 * Hh;
        }
        lds_barrier();   // LDS-only: global loads/stores remain in flight
    };

    for (int t = 0; t < T - 2; t += 2) {
        do_step(0, xq0, pf0, true, false);
        do_step(1, xq1, pf1, true, false);
    }
    do_step(0, xq0, pf0, false, false);   // t = 510
    do_step(1, xq1, pf1, false, true);    // t = 511, writes h_n
}

// ---------------- GEMM3: tags = sigmoid(min(hid,1) @ W_out^T + b_out) ----------------
// 512 thr (8 waves), M-tile 128, N-half 256 per block (128-KB stage). (round-3 form + cap)
__global__ __launch_bounds__(512, 2) void gemm3_tags(const _Float16* __restrict__ A,   // UNCAPPED h f16
                                                     const _Float16* __restrict__ Bw,  // W_out f16 [512,256]
                                                     const float* __restrict__ bias,
                                                     float* __restrict__ C) {
    const int K = 256, N = 512;
    __shared__ _Float16 ldsB[65536];     // 256 rows x 256 halves, 128 KB
    int wave = threadIdx.x >> 6;
    int lane = threadIdx.x & 63;
    int row  = lane & 15;
    int quad = lane >> 4;
    int m0 = blockIdx.x * 128 + wave * 16;
    int nb = blockIdx.y;                 // N-half

    stage_weights_swz(Bw + (size_t)nb * 256 * K, K, ldsB);   // W_out[nb*256 .. +256)

    floatx4 acc[16];
#pragma unroll
    for (int i = 0; i < 16; i++) acc[i] = (floatx4){0.f, 0.f, 0.f, 0.f};

    const _Float16* pa = A + (size_t)(m0 + row) * K + quad * 8;
    const char* lb = (const char*)ldsB;
    const _Float16 one = (_Float16)1.0f;

    for (int kk = 0; kk < 256; kk += 32) {
        half8 a = *(const half8*)(pa + kk);
        // capped_lrelu: h >= 0 (post-relu), so cap = min(h, 1), applied here
        // instead of in the RNN's serial loop (exact f16 min, bit-identical).
#pragma unroll
        for (int j = 0; j < 8; j++) a[j] = (a[j] < one) ? a[j] : one;
#pragma unroll
        for (int nt = 0; nt < 16; nt++) {
            int n = nt * 16 + row;
            int byte = n * 512 + ((quad * 16 + kk * 2) ^ ((n & 7) << 4));
            half8 b = *(const half8*)(lb + byte);
            acc[nt] = __builtin_amdgcn_mfma_f32_16x16x32_f16(a, b, acc[nt], 0, 0, 0);
        }
    }
#pragma unroll
    for (int nt = 0; nt < 16; nt++) {
        int n = nb * 256 + nt * 16 + row;
        float bn = bias[n];
#pragma unroll
        for (int r = 0; r < 4; r++) {
            int m = m0 + quad * 4 + r;
            float v = acc[nt][r] + bn;
            C[(size_t)m * N + n] = 1.f / (1.f + __expf(-v));
        }
    }
}

extern "C" void kernel_launch(void* const* d_in, const int* in_sizes, int n_in,
                              void* d_out, int out_size, void* d_ws, size_t ws_size,
                              hipStream_t stream) {
    const float* sentence   = (const float*)d_in[0];  // [64,512,512]
    const float* prev_state = (const float*)d_in[1];  // [1,64,256]
    const float* W_ih       = (const float*)d_in[2];  // [256,512]
    const float* b_ih       = (const float*)d_in[3];  // [256]
    const float* W_hh       = (const float*)d_in[4];  // [256,256]
    const float* b_hh       = (const float*)d_in[5];  // [256]
    const float* W_out      = (const float*)d_in[6];  // [512,256]
    const float* b_out      = (const float*)d_in[7];  // [512]

    const size_t WIH_N   = 256u * 512u;
    const size_t WOUT_N  = 512u * 256u;
    const size_t XPROJ_N = 32768u * 256u;
    const size_t HID_N   = 64u * 512u * 256u;

    char* w = (char*)d_ws;
    _Float16* wih_f  = (_Float16*)w;  w += WIH_N * sizeof(_Float16);
    _Float16* wout_f = (_Float16*)w;  w += WOUT_N * sizeof(_Float16);
    float*    xproj  = (float*)w;     w += XPROJ_N * sizeof(float);
    _Float16* hid_f  = (_Float16*)w;  w += HID_N * sizeof(_Float16);

    float* tags = (float*)d_out;
    float* h_n  = (float*)d_out + 16777216;

    // both f16 weight buffers in one launch (contiguous in ws)
    conv_weights<<<256, 256, 0, stream>>>(W_ih, W_out, wih_f);

    gemm1_xproj<<<256, 512, 0, stream>>>(sentence, wih_f, b_ih, b_hh, xproj);

    rnn_recur<<<4, 256, 0, stream>>>(xproj, prev_state, W_hh, hid_f, h_n);

    gemm3_tags<<<dim3(256, 2), 512, 0, stream>>>(hid_f, wout_f, b_out, tags);
}

// Round 7
// 515.834 us; speedup vs baseline: 1.2002x; 1.2002x over previous
//
#include <hip/hip_runtime.h>
#include <hip/hip_bf16.h>

// Dims: B=64, T=512, V=512, H=256, O=512. M1 = B*T = 32768.
// d_in: sentence, prev_state, W_ih, b_ih, W_hh, b_hh, W_out, b_out
// d_out: tags [B,T,O] fp32 (16777216) then h_n [1,B,H] fp32 (16384)
//
// Round 7:
//  - RNN: exact round-5 revert (368us known-good). Round-6 proved the step is
//    TLP-bound: 4 waves (1/SIMD, 144 VGPR) = 462us despite halved LDS reads.
//    8 waves x 2nt x 2/SIMD is the local optimum for this recurrence.
//  - GEMMs: the serial kk-loop consumed its A-load immediately (16 MFMA = 78cy
//    << 200-900cy load latency -> per-kk stall if compiler doesn't pipeline).
//    Explicit 2-deep A-prefetch: slot loaded at kk is consumed at kk+64, with
//    ~300cy of MFMA+LDS work in between. Fully unrolled so slots are
//    compile-time indexed (no scratch).

typedef __attribute__((ext_vector_type(8))) _Float16 half8;
typedef __attribute__((ext_vector_type(4))) _Float16 half4;
typedef __attribute__((ext_vector_type(4))) float   floatx4;

// LDS-only barrier: waits LDS ops, does NOT drain vmcnt — global loads/stores
// stay in flight across it.
__device__ __forceinline__ void lds_barrier() {
    asm volatile("s_waitcnt lgkmcnt(0)\n\ts_barrier" ::: "memory");
}

// ---------------- fp32 -> fp16 convert: W_ih and W_out in one launch ----------------
__global__ void conv_weights(const float* __restrict__ wih, const float* __restrict__ wout,
                             _Float16* __restrict__ out) {
    int idx = blockIdx.x * blockDim.x + threadIdx.x;   // 0..65535 quads
    const float* src = (idx < 32768) ? wih : wout;
    int j = idx & 32767;
    float4 v = ((const float4*)src)[j];
    half4 h = { (_Float16)v.x, (_Float16)v.y, (_Float16)v.z, (_Float16)v.w };
    ((half4*)out)[idx] = h;
}

// Stage 256 LDS rows x 512 B from f16 weights, XOR-swizzled within each row.
// LDS dest linear (global_load_lds requirement, m104); swizzle applied to the
// per-lane GLOBAL source address (m173). 512 threads.
__device__ __forceinline__ void stage_weights_swz(const _Float16* __restrict__ src,
                                                  int rowStrideHalves,
                                                  _Float16* lds) {
    int wave = threadIdx.x >> 6;
    int lane = threadIdx.x & 63;
#pragma unroll
    for (int j = 0; j < 16; j++) {
        int Lb = j * 8192 + wave * 1024 + lane * 16;   // this lane's LDS byte
        int n  = Lb >> 9;
        int c  = Lb & 511;
        int cs = c ^ ((n & 7) << 4);
        const _Float16* g = src + (size_t)n * rowStrideHalves + (cs >> 1);
        _Float16* l = lds + (j * 8192 + wave * 1024) / 2;   // wave-uniform base
        __builtin_amdgcn_global_load_lds((const __attribute__((address_space(1))) void*)g,
                                         (__attribute__((address_space(3))) void*)l,
                                         16, 0, 0);
    }
    asm volatile("s_waitcnt vmcnt(0)" ::: "memory");
    __syncthreads();
}

// ---------------- GEMM1: xproj = sentence [32768,512] @ W_ih^T + (b_ih+b_hh) ----------------
// 512 thr (8 waves), M-tile 128, K split in two 128-KB LDS stages.
// A-loads 2-deep prefetched across the kk loop.
__global__ __launch_bounds__(512, 2) void gemm1_xproj(const float* __restrict__ A,
                                                      const _Float16* __restrict__ Bw,  // W_ih f16 [256,512]
                                                      const float* __restrict__ b_ih,
                                                      const float* __restrict__ b_hh,
                                                      float* __restrict__ C) {          // [32768,256]
    const int K = 512, N = 256;
    __shared__ _Float16 ldsB[65536];     // 256 rows x 256 halves (one K-half), 128 KB
    int wave = threadIdx.x >> 6;
    int lane = threadIdx.x & 63;
    int row  = lane & 15;
    int quad = lane >> 4;
    int m0 = blockIdx.x * 128 + wave * 16;

    floatx4 acc[16];
#pragma unroll
    for (int i = 0; i < 16; i++) acc[i] = (floatx4){0.f, 0.f, 0.f, 0.f};

    const float* pa = A + (size_t)(m0 + row) * K + quad * 8;
    const char* lb = (const char*)ldsB;

    // 2-deep A prefetch slots (issued BEFORE the stage so they overlap its drain)
    float4 a0s[2], a1s[2];
    a0s[0] = *(const float4*)(pa + 0);   a1s[0] = *(const float4*)(pa + 4);
    a0s[1] = *(const float4*)(pa + 32);  a1s[1] = *(const float4*)(pa + 36);

    for (int h = 0; h < 2; h++) {
        if (h) __syncthreads();                       // all waves done reading half 0
        stage_weights_swz(Bw + h * 256, 512, ldsB);   // wih[:, h*256 : h*256+256]

#pragma unroll
        for (int kk = 0; kk < 256; kk += 32) {
            int kg = h * 256 + kk;            // global k (compile-time in unroll)
            int s  = (kg >> 5) & 1;
            float4 a0 = a0s[s], a1 = a1s[s];
            if (kg + 64 < 512) {              // refill slot for kk+64
                a0s[s] = *(const float4*)(pa + kg + 64);
                a1s[s] = *(const float4*)(pa + kg + 68);
            }
            half8 a = { (_Float16)a0.x, (_Float16)a0.y, (_Float16)a0.z, (_Float16)a0.w,
                        (_Float16)a1.x, (_Float16)a1.y, (_Float16)a1.z, (_Float16)a1.w };
#pragma unroll
            for (int nt = 0; nt < 16; nt++) {
                int n = nt * 16 + row;
                int byte = n * 512 + ((quad * 16 + kk * 2) ^ ((n & 7) << 4));
                half8 b = *(const half8*)(lb + byte);
                acc[nt] = __builtin_amdgcn_mfma_f32_16x16x32_f16(a, b, acc[nt], 0, 0, 0);
            }
        }
    }
#pragma unroll
    for (int nt = 0; nt < 16; nt++) {
        int n = nt * 16 + row;
        float bn = b_ih[n] + b_hh[n];
#pragma unroll
        for (int r = 0; r < 4; r++) {
            int m = m0 + quad * 4 + r;
            C[(size_t)m * N + n] = acc[nt][r] + bn;
        }
    }
}

// ---------------- Recurrence: 4 blocks x 16 batch rows, 512 threads (8 waves, 2/SIMD) ----------------
// EXACT round-5 kernel (368us measured).
__global__ __launch_bounds__(512, 2) void rnn_recur(const float* __restrict__ xp,    // [B,T,H] fp32 (bias incl.)
                                                    const float* __restrict__ h0,    // [1,B,H] fp32
                                                    const float* __restrict__ W_hh,  // [H,H] fp32
                                                    _Float16* __restrict__ hid,      // f16 [B,T,H] UNCAPPED
                                                    float* __restrict__ h_n) {       // [B,H] fp32
    const int Hh = 256, T = 512, LD = 264;   // LDS row stride in halves
    int b0   = blockIdx.x * 16;
    int wave = threadIdx.x >> 6;
    int lane = threadIdx.x & 63;
    int c    = lane & 15;       // batch col within tile
    int q    = lane >> 4;

    half8 wf[2][8];
#pragma unroll
    for (int nt = 0; nt < 2; nt++) {
        int n = (wave * 2 + nt) * 16 + c;
        const float* wr = W_hh + (size_t)n * Hh + q * 8;
#pragma unroll
        for (int kt = 0; kt < 8; kt++) {
            float4 x0 = *(const float4*)(wr + kt * 32);
            float4 x1 = *(const float4*)(wr + kt * 32 + 4);
            wf[nt][kt] = (half8){ (_Float16)x0.x, (_Float16)x0.y, (_Float16)x0.z, (_Float16)x0.w,
                                  (_Float16)x1.x, (_Float16)x1.y, (_Float16)x1.z, (_Float16)x1.w };
        }
    }

    __shared__ _Float16 hb[2][16][264];
    for (int idx = threadIdx.x; idx < 16 * 256; idx += 512) {
        int m = idx >> 8, k = idx & 255;
        hb[0][m][k] = (_Float16)h0[(size_t)(b0 + m) * Hh + k];
    }
    __syncthreads();   // once, before the loop

    const float* xpb = xp + (size_t)(b0 + c) * T * Hh;
    _Float16* hidb = hid + (size_t)(b0 + c) * T * Hh;

    int noff[2];
#pragma unroll
    for (int nt = 0; nt < 2; nt++) noff[nt] = (wave * 2 + nt) * 16 + q * 4;

    // two prefetch slots: slot0 = even steps, slot1 = odd steps
    float4 xq0[2], xq1[2];
#pragma unroll
    for (int nt = 0; nt < 2; nt++) {
        xq0[nt] = *(const float4*)(xpb + (size_t)0 * Hh + noff[nt]);
        xq1[nt] = *(const float4*)(xpb + (size_t)1 * Hh + noff[nt]);
    }
    const float* pf0 = xpb + 2 * Hh;   // slot0's next load: x[t+2]
    const float* pf1 = xpb + 3 * Hh;   // slot1's next load: x[t+3]
    _Float16* hp = hidb;               // hid row for current t, advanced per step

    auto do_step = [&](int parity, float4 (&xq)[2], const float*& pf,
                       bool prefetch, bool last) {
        const _Float16* hr = &hb[parity][0][0];
        // 4 independent zero-init chains; xq added AFTER the chains (round-4
        // lesson: xq at chain head forces a vmcnt drain right after the barrier).
        floatx4 aA0 = {0.f,0.f,0.f,0.f}, aA1 = {0.f,0.f,0.f,0.f};
        floatx4 aB0 = {0.f,0.f,0.f,0.f}, aB1 = {0.f,0.f,0.f,0.f};
#pragma unroll
        for (int kt = 0; kt < 4; kt++) {
            half8 hfA = *(const half8*)(hr + c * LD + kt * 32 + q * 8);
            half8 hfB = *(const half8*)(hr + c * LD + (kt + 4) * 32 + q * 8);
            aA0 = __builtin_amdgcn_mfma_f32_16x16x32_f16(wf[0][kt],     hfA, aA0, 0, 0, 0);
            aB0 = __builtin_amdgcn_mfma_f32_16x16x32_f16(wf[0][kt + 4], hfB, aB0, 0, 0, 0);
            aA1 = __builtin_amdgcn_mfma_f32_16x16x32_f16(wf[1][kt],     hfA, aA1, 0, 0, 0);
            aB1 = __builtin_amdgcn_mfma_f32_16x16x32_f16(wf[1][kt + 4], hfB, aB1, 0, 0, 0);
        }
        floatx4 acc[2];
        acc[0] = aA0 + aB0;
        acc[1] = aA1 + aB1;

        _Float16* hw = &hb[parity ^ 1][0][0];
#pragma unroll
        for (int nt = 0; nt < 2; nt++) {
            float v0 = fmaxf(acc[nt][0] + xq[nt].x, 0.f);
            float v1 = fmaxf(acc[nt][1] + xq[nt].y, 0.f);
            float v2 = fmaxf(acc[nt][2] + xq[nt].z, 0.f);
            float v3 = fmaxf(acc[nt][3] + xq[nt].w, 0.f);
            half4 hv = { (_Float16)v0, (_Float16)v1, (_Float16)v2, (_Float16)v3 };
            *(half4*)(hw + c * LD + noff[nt]) = hv;   // next step's B source
            *(half4*)(hp + noff[nt]) = hv;            // UNCAPPED hidden; gemm3 caps
            if (last) {
                float4 hn = { v0, v1, v2, v3 };
                *(float4*)(h_n + (size_t)(b0 + c) * Hh + noff[nt]) = hn;
            }
        }
        hp += Hh;
        if (prefetch) {
#pragma unroll
            for (int nt = 0; nt < 2; nt++)
                xq[nt] = *(const float4*)(pf + noff[nt]);
            pf += 2 * Hh;
        }
        lds_barrier();   // LDS-only: global loads/stores remain in flight
    };

    for (int t = 0; t < T - 2; t += 2) {
        do_step(0, xq0, pf0, true, false);
        do_step(1, xq1, pf1, true, false);
    }
    do_step(0, xq0, pf0, false, false);   // t = 510
    do_step(1, xq1, pf1, false, true);    // t = 511, writes h_n
}

// ---------------- GEMM3: tags = sigmoid(min(hid,1) @ W_out^T + b_out) ----------------
// 512 thr (8 waves), M-tile 128, N-half 256 per block (128-KB stage).
// A-loads 2-deep prefetched across the kk loop.
__global__ __launch_bounds__(512, 2) void gemm3_tags(const _Float16* __restrict__ A,   // UNCAPPED h f16
                                                     const _Float16* __restrict__ Bw,  // W_out f16 [512,256]
                                                     const float* __restrict__ bias,
                                                     float* __restrict__ C) {
    const int K = 256, N = 512;
    __shared__ _Float16 ldsB[65536];     // 256 rows x 256 halves, 128 KB
    int wave = threadIdx.x >> 6;
    int lane = threadIdx.x & 63;
    int row  = lane & 15;
    int quad = lane >> 4;
    int m0 = blockIdx.x * 128 + wave * 16;
    int nb = blockIdx.y;                 // N-half

    const _Float16* pa = A + (size_t)(m0 + row) * K + quad * 8;

    // 2-deep A prefetch slots (issued BEFORE the stage so they overlap its drain)
    half8 as[2];
    as[0] = *(const half8*)(pa + 0);
    as[1] = *(const half8*)(pa + 32);

    stage_weights_swz(Bw + (size_t)nb * 256 * K, K, ldsB);   // W_out[nb*256 .. +256)

    floatx4 acc[16];
#pragma unroll
    for (int i = 0; i < 16; i++) acc[i] = (floatx4){0.f, 0.f, 0.f, 0.f};

    const char* lb = (const char*)ldsB;
    const _Float16 one = (_Float16)1.0f;

#pragma unroll
    for (int kk = 0; kk < 256; kk += 32) {
        int s = (kk >> 5) & 1;
        half8 a = as[s];
        if (kk + 64 < 256)
            as[s] = *(const half8*)(pa + kk + 64);
        // capped_lrelu: h >= 0 (post-relu), so cap = min(h, 1), applied here
        // instead of in the RNN's serial loop (exact f16 min, bit-identical).
#pragma unroll
        for (int j = 0; j < 8; j++) a[j] = (a[j] < one) ? a[j] : one;
#pragma unroll
        for (int nt = 0; nt < 16; nt++) {
            int n = nt * 16 + row;
            int byte = n * 512 + ((quad * 16 + kk * 2) ^ ((n & 7) << 4));
            half8 b = *(const half8*)(lb + byte);
            acc[nt] = __builtin_amdgcn_mfma_f32_16x16x32_f16(a, b, acc[nt], 0, 0, 0);
        }
    }
#pragma unroll
    for (int nt = 0; nt < 16; nt++) {
        int n = nb * 256 + nt * 16 + row;
        float bn = bias[n];
#pragma unroll
        for (int r = 0; r < 4; r++) {
            int m = m0 + quad * 4 + r;
            float v = acc[nt][r] + bn;
            C[(size_t)m * N + n] = 1.f / (1.f + __expf(-v));
        }
    }
}

extern "C" void kernel_launch(void* const* d_in, const int* in_sizes, int n_in,
                              void* d_out, int out_size, void* d_ws, size_t ws_size,
                              hipStream_t stream) {
    const float* sentence   = (const float*)d_in[0];  // [64,512,512]
    const float* prev_state = (const float*)d_in[1];  // [1,64,256]
    const float* W_ih       = (const float*)d_in[2];  // [256,512]
    const float* b_ih       = (const float*)d_in[3];  // [256]
    const float* W_hh       = (const float*)d_in[4];  // [256,256]
    const float* b_hh       = (const float*)d_in[5];  // [256]
    const float* W_out      = (const float*)d_in[6];  // [512,256]
    const float* b_out      = (const float*)d_in[7];  // [512]

    const size_t WIH_N   = 256u * 512u;
    const size_t WOUT_N  = 512u * 256u;
    const size_t XPROJ_N = 32768u * 256u;
    const size_t HID_N   = 64u * 512u * 256u;

    char* w = (char*)d_ws;
    _Float16* wih_f  = (_Float16*)w;  w += WIH_N * sizeof(_Float16);
    _Float16* wout_f = (_Float16*)w;  w += WOUT_N * sizeof(_Float16);
    float*    xproj  = (float*)w;     w += XPROJ_N * sizeof(float);
    _Float16* hid_f  = (_Float16*)w;  w += HID_N * sizeof(_Float16);

    float* tags = (float*)d_out;
    float* h_n  = (float*)d_out + 16777216;

    // both f16 weight buffers in one launch (contiguous in ws)
    conv_weights<<<256, 256, 0, stream>>>(W_ih, W_out, wih_f);

    gemm1_xproj<<<256, 512, 0, stream>>>(sentence, wih_f, b_ih, b_hh, xproj);

    rnn_recur<<<4, 512, 0, stream>>>(xproj, prev_state, W_hh, hid_f, h_n);

    gemm3_tags<<<dim3(256, 2), 512, 0, stream>>>(hid_f, wout_f, b_out, tags);
}